// Round 1
// baseline (129.924 us; speedup 1.0000x reference)
//
#include <hip/hip_runtime.h>

typedef unsigned short u16;
typedef __bf16 bf16x8 __attribute__((ext_vector_type(8)));
typedef float f32x4 __attribute__((ext_vector_type(4)));

#define GLD_LDS(gptr, lptr) \
  __builtin_amdgcn_global_load_lds((const __attribute__((address_space(1))) void*)(gptr), \
                                   (__attribute__((address_space(3))) void*)(lptr), 16, 0, 0)

__device__ __forceinline__ u16 f2b(float f) {
  union { __bf16 h; u16 u; } v; v.h = (__bf16)f; return v.u;
}
__device__ __forceinline__ float elu1(float v) {
  return v > 0.f ? v : (__expf(v) - 1.f);
}

// ---------------- convert kernels ----------------

__global__ void cvt_f32_bf16_vec4(const float* __restrict__ in, u16* __restrict__ out) {
  int i = blockIdx.x * blockDim.x + threadIdx.x;
  float4 v = reinterpret_cast<const float4*>(in)[i];
  ushort4 o;
  o.x = f2b(v.x); o.y = f2b(v.y); o.z = f2b(v.z); o.w = f2b(v.w);
  reinterpret_cast<ushort4*>(out)[i] = o;
}

// in: [z][R][C] f32  ->  out: [z][C][R] bf16   (R, C multiples of 32)
__global__ void tcvt(const float* __restrict__ in, u16* __restrict__ out, int R, int C) {
  __shared__ float t[32][33];
  const float* inp = in + (size_t)blockIdx.z * R * C;
  u16* outp = out + (size_t)blockIdx.z * R * C;
  int c0 = blockIdx.x * 32, r0 = blockIdx.y * 32;
  int tx = threadIdx.x, ty = threadIdx.y;
#pragma unroll
  for (int j = ty; j < 32; j += 8)
    t[j][tx] = inp[(size_t)(r0 + j) * C + c0 + tx];
  __syncthreads();
#pragma unroll
  for (int j = ty; j < 32; j += 8)
    outp[(size_t)(c0 + j) * R + r0 + tx] = f2b(t[tx][j]);
}

// ---------------- routing ----------------

__global__ void route_kernel(const int* __restrict__ cat, int* __restrict__ list,
                             int* __restrict__ off) {
  __shared__ int cnt[8];
  __shared__ int cur[8];
  __shared__ int offs[9];
  int t = threadIdx.x;
  if (t < 8) cnt[t] = 0;
  __syncthreads();
  for (int i = t; i < 8192; i += 1024) atomicAdd(&cnt[cat[i]], 1);
  __syncthreads();
  if (t == 0) {
    int s = 0;
    for (int e = 0; e < 8; e++) { offs[e] = s; s += cnt[e]; }
    offs[8] = s;
  }
  __syncthreads();
  if (t < 8) cur[t] = offs[t];
  if (t < 9) off[t] = offs[t];
  __syncthreads();
  for (int i = t; i < 8192; i += 1024) {
    int c = cat[i];
    int p = atomicAdd(&cur[c], 1);
    list[p] = i;
  }
}

// ---------------- GEMM layer 1 : mid = elu(x @ W_in + b_in) ----------------
// xb [8192][512] bf16, wt [1024][512] bf16 (N-major), midb [8192][1024] bf16

__global__ __launch_bounds__(256) void gemm_l1(const u16* __restrict__ xb,
                                               const u16* __restrict__ wt,
                                               const float* __restrict__ bias,
                                               u16* __restrict__ midb) {
  constexpr int K = 512, N = 1024;
  __shared__ alignas(16) u16 As[128 * 32];
  __shared__ alignas(16) u16 Bs[128 * 32];
  const int tid = threadIdx.x;
  const int wave = tid >> 6, lane = tid & 63;
  const int row0 = blockIdx.x * 128, col0 = blockIdx.y * 128;
  const int srow = tid >> 2;          // 0..63
  const int sk = (tid & 3) * 8;
  const u16* ga0 = xb + (size_t)(row0 + srow) * K + sk;
  const u16* ga1 = xb + (size_t)(row0 + 64 + srow) * K + sk;
  const u16* gb0 = wt + (size_t)(col0 + srow) * K + sk;
  const u16* gb1 = wt + (size_t)(col0 + 64 + srow) * K + sk;
  u16* lA0 = &As[(wave * 64) * 8];
  u16* lA1 = &As[(256 + wave * 64) * 8];
  u16* lB0 = &Bs[(wave * 64) * 8];
  u16* lB1 = &Bs[(256 + wave * 64) * 8];

  f32x4 acc[4][4] = {};
  const int wr = wave >> 1, wc = wave & 1;
  const int fr = lane & 15, kg = lane >> 4;
  const int arow = (wr * 64 + fr) * 32 + kg * 8;
  const int brow = (wc * 64 + fr) * 32 + kg * 8;

  for (int kt = 0; kt < K; kt += 32) {
    GLD_LDS(ga0 + kt, lA0);
    GLD_LDS(ga1 + kt, lA1);
    GLD_LDS(gb0 + kt, lB0);
    GLD_LDS(gb1 + kt, lB1);
    __syncthreads();
    bf16x8 af[4], bfv[4];
#pragma unroll
    for (int mr = 0; mr < 4; mr++) af[mr] = *(const bf16x8*)&As[arow + mr * 16 * 32];
#pragma unroll
    for (int nr = 0; nr < 4; nr++) bfv[nr] = *(const bf16x8*)&Bs[brow + nr * 16 * 32];
#pragma unroll
    for (int mr = 0; mr < 4; mr++)
#pragma unroll
      for (int nr = 0; nr < 4; nr++)
        acc[mr][nr] = __builtin_amdgcn_mfma_f32_16x16x32_bf16(af[mr], bfv[nr], acc[mr][nr], 0, 0, 0);
    __syncthreads();
  }

#pragma unroll
  for (int nr = 0; nr < 4; nr++) {
    int col = col0 + wc * 64 + nr * 16 + fr;
    float bc = bias[col];
#pragma unroll
    for (int mr = 0; mr < 4; mr++) {
      int row = row0 + wr * 64 + mr * 16 + kg * 4;
#pragma unroll
      for (int j = 0; j < 4; j++) {
        float v = acc[mr][nr][j] + bc;
        midb[(size_t)(row + j) * N + col] = f2b(elu1(v));
      }
    }
  }
}

// ---------------- GEMM layer 2 (grouped) : h = elu(mid[rows_e] @ W1[e] + b1[e]) ----------------
// midb [8192][1024], w1t [8][512][1024] (N-major), hb [8192][512] compact by expert

__global__ __launch_bounds__(256) void gemm_l2(const u16* __restrict__ midb,
                                               const u16* __restrict__ w1t,
                                               const float* __restrict__ b1,
                                               const int* __restrict__ list,
                                               const int* __restrict__ off,
                                               u16* __restrict__ hb) {
  constexpr int K = 1024, N = 512;
  const int e = blockIdx.z;
  const int start = off[e];
  const int cnt = off[e + 1] - start;
  if ((int)blockIdx.x * 128 >= cnt) return;

  __shared__ alignas(16) u16 As[128 * 32];
  __shared__ alignas(16) u16 Bs[128 * 32];
  const int tid = threadIdx.x;
  const int wave = tid >> 6, lane = tid & 63;
  const int col0 = blockIdx.y * 128;
  const int srow = tid >> 2;
  const int sk = (tid & 3) * 8;
  int slot0 = blockIdx.x * 128 + srow;
  int g0 = list[start + min(slot0, cnt - 1)];
  int g1 = list[start + min(slot0 + 64, cnt - 1)];
  const u16* ga0 = midb + (size_t)g0 * K + sk;
  const u16* ga1 = midb + (size_t)g1 * K + sk;
  const u16* wte = w1t + (size_t)e * N * K;
  const u16* gb0 = wte + (size_t)(col0 + srow) * K + sk;
  const u16* gb1 = wte + (size_t)(col0 + 64 + srow) * K + sk;
  u16* lA0 = &As[(wave * 64) * 8];
  u16* lA1 = &As[(256 + wave * 64) * 8];
  u16* lB0 = &Bs[(wave * 64) * 8];
  u16* lB1 = &Bs[(256 + wave * 64) * 8];

  f32x4 acc[4][4] = {};
  const int wr = wave >> 1, wc = wave & 1;
  const int fr = lane & 15, kg = lane >> 4;
  const int arow = (wr * 64 + fr) * 32 + kg * 8;
  const int brow = (wc * 64 + fr) * 32 + kg * 8;

  for (int kt = 0; kt < K; kt += 32) {
    GLD_LDS(ga0 + kt, lA0);
    GLD_LDS(ga1 + kt, lA1);
    GLD_LDS(gb0 + kt, lB0);
    GLD_LDS(gb1 + kt, lB1);
    __syncthreads();
    bf16x8 af[4], bfv[4];
#pragma unroll
    for (int mr = 0; mr < 4; mr++) af[mr] = *(const bf16x8*)&As[arow + mr * 16 * 32];
#pragma unroll
    for (int nr = 0; nr < 4; nr++) bfv[nr] = *(const bf16x8*)&Bs[brow + nr * 16 * 32];
#pragma unroll
    for (int mr = 0; mr < 4; mr++)
#pragma unroll
      for (int nr = 0; nr < 4; nr++)
        acc[mr][nr] = __builtin_amdgcn_mfma_f32_16x16x32_bf16(af[mr], bfv[nr], acc[mr][nr], 0, 0, 0);
    __syncthreads();
  }

#pragma unroll
  for (int nr = 0; nr < 4; nr++) {
    int col = col0 + wc * 64 + nr * 16 + fr;
    float bc = b1[(size_t)e * N + col];
#pragma unroll
    for (int mr = 0; mr < 4; mr++) {
      int sbase = blockIdx.x * 128 + wr * 64 + mr * 16 + kg * 4;
#pragma unroll
      for (int j = 0; j < 4; j++) {
        int slotr = sbase + j;
        if (slotr < cnt) {
          float v = acc[mr][nr][j] + bc;
          hb[(size_t)(start + slotr) * N + col] = f2b(elu1(v));
        }
      }
    }
  }
}

// ---------------- GEMM layer 3 (grouped) : out[row] = h @ W2[e] + b2[e] ----------------
// hb [8192][512] compact, w2t [8][64][512] (N-major), out [8192][64] f32 scattered

__global__ __launch_bounds__(256) void gemm_l3(const u16* __restrict__ hb,
                                               const u16* __restrict__ w2t,
                                               const float* __restrict__ b2,
                                               const int* __restrict__ list,
                                               const int* __restrict__ off,
                                               float* __restrict__ out) {
  constexpr int K = 512, N = 64;
  const int e = blockIdx.z;
  const int start = off[e];
  const int cnt = off[e + 1] - start;
  if ((int)blockIdx.x * 128 >= cnt) return;

  __shared__ alignas(16) u16 As[128 * 32];
  __shared__ alignas(16) u16 Bs[64 * 32];
  const int tid = threadIdx.x;
  const int wave = tid >> 6, lane = tid & 63;
  const int srow = tid >> 2;
  const int sk = (tid & 3) * 8;
  int slot0 = blockIdx.x * 128 + srow;
  const u16* ga0 = hb + (size_t)(start + min(slot0, cnt - 1)) * K + sk;
  const u16* ga1 = hb + (size_t)(start + min(slot0 + 64, cnt - 1)) * K + sk;
  const u16* gb0 = w2t + (size_t)e * N * K + (size_t)srow * K + sk;  // srow = col 0..63
  u16* lA0 = &As[(wave * 64) * 8];
  u16* lA1 = &As[(256 + wave * 64) * 8];
  u16* lB0 = &Bs[(wave * 64) * 8];

  f32x4 acc[4][2] = {};
  const int wr = wave >> 1, wc = wave & 1;
  const int fr = lane & 15, kg = lane >> 4;
  const int arow = (wr * 64 + fr) * 32 + kg * 8;
  const int brow = (wc * 32 + fr) * 32 + kg * 8;

  for (int kt = 0; kt < K; kt += 32) {
    GLD_LDS(ga0 + kt, lA0);
    GLD_LDS(ga1 + kt, lA1);
    GLD_LDS(gb0 + kt, lB0);
    __syncthreads();
    bf16x8 af[4], bfv[2];
#pragma unroll
    for (int mr = 0; mr < 4; mr++) af[mr] = *(const bf16x8*)&As[arow + mr * 16 * 32];
#pragma unroll
    for (int nr = 0; nr < 2; nr++) bfv[nr] = *(const bf16x8*)&Bs[brow + nr * 16 * 32];
#pragma unroll
    for (int mr = 0; mr < 4; mr++)
#pragma unroll
      for (int nr = 0; nr < 2; nr++)
        acc[mr][nr] = __builtin_amdgcn_mfma_f32_16x16x32_bf16(af[mr], bfv[nr], acc[mr][nr], 0, 0, 0);
    __syncthreads();
  }

#pragma unroll
  for (int nr = 0; nr < 2; nr++) {
    int col = wc * 32 + nr * 16 + fr;
    float bc = b2[(size_t)e * N + col];
#pragma unroll
    for (int mr = 0; mr < 4; mr++) {
      int sbase = blockIdx.x * 128 + wr * 64 + mr * 16 + kg * 4;
#pragma unroll
      for (int j = 0; j < 4; j++) {
        int slotr = sbase + j;
        if (slotr < cnt) {
          int gr = list[start + slotr];
          out[(size_t)gr * 64 + col] = acc[mr][nr][j] + bc;
        }
      }
    }
  }
}

// ---------------- launch ----------------

extern "C" void kernel_launch(void* const* d_in, const int* in_sizes, int n_in,
                              void* d_out, int out_size, void* d_ws, size_t ws_size,
                              hipStream_t stream) {
  const float* x    = (const float*)d_in[0];
  const int*   cat  = (const int*)d_in[1];
  const float* W_in = (const float*)d_in[2];
  const float* b_in = (const float*)d_in[3];
  const float* W1   = (const float*)d_in[4];
  const float* b1   = (const float*)d_in[5];
  const float* W2   = (const float*)d_in[6];
  const float* b2   = (const float*)d_in[7];
  float* out = (float*)d_out;

  char* p = (char*)d_ws;
  u16* xb   = (u16*)p; p += (size_t)8192 * 512 * 2;    // 8 MB
  u16* midb = (u16*)p; p += (size_t)8192 * 1024 * 2;   // 16 MB
  u16* hb   = (u16*)p; p += (size_t)8192 * 512 * 2;    // 8 MB
  u16* wtin = (u16*)p; p += (size_t)1024 * 512 * 2;    // 1 MB
  u16* w1t  = (u16*)p; p += (size_t)8 * 512 * 1024 * 2;// 8 MB
  u16* w2t  = (u16*)p; p += (size_t)8 * 64 * 512 * 2;  // 0.5 MB
  int* list = (int*)p; p += (size_t)8192 * 4;          // 32 KB
  int* off  = (int*)p; p += 64;

  // converts
  cvt_f32_bf16_vec4<<<4096, 256, 0, stream>>>(x, xb);                 // 8192*512
  tcvt<<<dim3(32, 16, 1), dim3(32, 8), 0, stream>>>(W_in, wtin, 512, 1024);
  tcvt<<<dim3(16, 32, 8), dim3(32, 8), 0, stream>>>(W1, w1t, 1024, 512);
  tcvt<<<dim3(2, 16, 8), dim3(32, 8), 0, stream>>>(W2, w2t, 512, 64);

  // routing
  route_kernel<<<1, 1024, 0, stream>>>(cat, list, off);

  // layer 1: [8192,512] @ [512,1024]
  gemm_l1<<<dim3(64, 8), 256, 0, stream>>>(xb, wtin, b_in, midb);
  // layer 2 grouped: [cnt_e,1024] @ [1024,512]
  gemm_l2<<<dim3(64, 4, 8), 256, 0, stream>>>(midb, w1t, b1, list, off, hb);
  // layer 3 grouped: [cnt_e,512] @ [512,64]
  gemm_l3<<<dim3(64, 1, 8), 256, 0, stream>>>(hb, w2t, b2, list, off, out);
}

// Round 2
// 84.784 us; speedup vs baseline: 1.5324x; 1.5324x over previous
//
#include <hip/hip_runtime.h>

typedef unsigned short u16;
typedef __bf16 bf16x8 __attribute__((ext_vector_type(8)));
typedef float f32x4 __attribute__((ext_vector_type(4)));

#define GLD_LDS(gptr, lptr) \
  __builtin_amdgcn_global_load_lds((const __attribute__((address_space(1))) void*)(gptr), \
                                   (__attribute__((address_space(3))) void*)(lptr), 16, 0, 0)

__device__ __forceinline__ u16 f2b(float f) {
  union { __bf16 h; u16 u; } v; v.h = (__bf16)f; return v.u;
}
__device__ __forceinline__ float elu1(float v) {
  return v > 0.f ? v : (__expf(v) - 1.f);
}

// ---------------- convert kernels ----------------

__global__ void cvt_f32_bf16_vec4(const float* __restrict__ in, u16* __restrict__ out) {
  int i = blockIdx.x * blockDim.x + threadIdx.x;
  float4 v = reinterpret_cast<const float4*>(in)[i];
  ushort4 o;
  o.x = f2b(v.x); o.y = f2b(v.y); o.z = f2b(v.z); o.w = f2b(v.w);
  reinterpret_cast<ushort4*>(out)[i] = o;
}

// in: [z][R][C] f32  ->  out: [z][C][R] bf16   (R, C multiples of 32)
__global__ void tcvt(const float* __restrict__ in, u16* __restrict__ out, int R, int C) {
  __shared__ float t[32][33];
  const float* inp = in + (size_t)blockIdx.z * R * C;
  u16* outp = out + (size_t)blockIdx.z * R * C;
  int c0 = blockIdx.x * 32, r0 = blockIdx.y * 32;
  int tx = threadIdx.x, ty = threadIdx.y;
#pragma unroll
  for (int j = ty; j < 32; j += 8)
    t[j][tx] = inp[(size_t)(r0 + j) * C + c0 + tx];
  __syncthreads();
#pragma unroll
  for (int j = ty; j < 32; j += 8)
    outp[(size_t)(c0 + j) * R + r0 + tx] = f2b(t[tx][j]);
}

// ---------------- routing ----------------

__global__ void route_kernel(const int* __restrict__ cat, int* __restrict__ list,
                             int* __restrict__ off) {
  __shared__ int cnt[8];
  __shared__ int cur[8];
  __shared__ int offs[9];
  int t = threadIdx.x;
  if (t < 8) cnt[t] = 0;
  __syncthreads();
  for (int i = t; i < 8192; i += 1024) atomicAdd(&cnt[cat[i]], 1);
  __syncthreads();
  if (t == 0) {
    int s = 0;
    for (int e = 0; e < 8; e++) { offs[e] = s; s += cnt[e]; }
    offs[8] = s;
  }
  __syncthreads();
  if (t < 8) cur[t] = offs[t];
  if (t < 9) off[t] = offs[t];
  __syncthreads();
  for (int i = t; i < 8192; i += 1024) {
    int c = cat[i];
    int p = atomicAdd(&cur[c], 1);
    list[p] = i;
  }
}

// ---------------- unified pipelined GEMM ----------------
// BM = 64, BK = 32, 4 waves (2x2), wave-tile 32 x (BN/2).
// A [.][K] bf16; Bw [E][N][K] bf16 (N-major); 2-stage prefetch pipeline.
// LAYER 1: dense rows, bf16 out + ELU.
// LAYER 2: rows gathered via list, compact bf16 out + ELU.
// LAYER 3: compact rows in, f32 out scattered via list, no activation.

template<int LAYER, int BN, int K, int N>
__global__ __launch_bounds__(256, 4) void gemm_t(
    const u16* __restrict__ A, const u16* __restrict__ Bw,
    const float* __restrict__ bias,
    const int* __restrict__ list, const int* __restrict__ off,
    u16* __restrict__ outb, float* __restrict__ outf) {
  __shared__ alignas(16) u16 As[2][64 * 32];
  __shared__ alignas(16) u16 Bs[2][BN * 32];

  const int tid = threadIdx.x;
  const int wave = tid >> 6, lane = tid & 63;

  int e = 0, start = 0, cnt = 0, rowbase;
  if constexpr (LAYER == 1) {
    rowbase = blockIdx.x * 64;
  } else {
    int t = blockIdx.x;
    int found = -1;
    for (e = 0; e < 8; e++) {
      int tiles = (off[e + 1] - off[e] + 63) >> 6;
      if (t < tiles) { found = e; break; }
      t -= tiles;
    }
    if (found < 0) return;
    start = off[e];
    cnt = off[e + 1] - start;
    rowbase = t * 64;
  }
  const int col0 = blockIdx.y * BN;

  // staging addresses: thread t stages (row = t>>2, chunk = t&3), source chunk
  // is XOR-swizzled so LDS (linear dest) holds the swizzled layout.
  const int srow = tid >> 2, skc = tid & 3;
  const int kxs = (skc ^ (srow & 3)) * 8;

  const u16* a_src;
  if constexpr (LAYER == 1) {
    a_src = A + (size_t)(rowbase + srow) * K + kxs;
  } else if constexpr (LAYER == 2) {
    int slot = rowbase + srow;
    int gr = list[start + min(slot, cnt - 1)];
    a_src = A + (size_t)gr * K + kxs;
  } else {
    int slot = rowbase + srow;
    a_src = A + (size_t)(start + min(slot, cnt - 1)) * K + kxs;
  }
  const u16* Bbase = Bw + (LAYER == 1 ? (size_t)0 : (size_t)e * N * K);
  const u16* b_src0 = Bbase + (size_t)(col0 + srow) * K + kxs;
  const u16* b_src1 = Bbase + (size_t)(col0 + 64 + srow) * K + kxs;  // only BN==128

  const int wbase = wave * 64 * 8;  // wave-uniform LDS dest base (elems)

  // fragment read offsets (swizzled)
  constexpr int NR = BN / 32;
  const int wy = wave & 1, wx = wave >> 1;
  const int fr = lane & 15, kg = lane >> 4;
  const int kx = (kg ^ (fr & 3)) * 8;
  const int ar0 = (wy * 32 + fr) * 32 + kx;
  const int br0 = (wx * (BN / 2) + fr) * 32 + kx;

  f32x4 acc[2][NR] = {};

  // prologue
  GLD_LDS(a_src, &As[0][wbase]);
  GLD_LDS(b_src0, &Bs[0][wbase]);
  if constexpr (BN == 128) GLD_LDS(b_src1, &Bs[0][2048 + wbase]);
  __syncthreads();

  constexpr int NK = K / 32;
  for (int t = 0; t < NK; ++t) {
    const int cur = t & 1;
    if (t + 1 < NK) {  // prefetch next tile into other buffer (in flight across compute)
      const int nxt = cur ^ 1;
      const int kt = (t + 1) * 32;
      GLD_LDS(a_src + kt, &As[nxt][wbase]);
      GLD_LDS(b_src0 + kt, &Bs[nxt][wbase]);
      if constexpr (BN == 128) GLD_LDS(b_src1 + kt, &Bs[nxt][2048 + wbase]);
    }
    bf16x8 af[2], bfv[NR];
#pragma unroll
    for (int m = 0; m < 2; m++) af[m] = *(const bf16x8*)&As[cur][ar0 + m * 16 * 32];
#pragma unroll
    for (int n = 0; n < NR; n++) bfv[n] = *(const bf16x8*)&Bs[cur][br0 + n * 16 * 32];
#pragma unroll
    for (int m = 0; m < 2; m++)
#pragma unroll
      for (int n = 0; n < NR; n++)
        acc[m][n] = __builtin_amdgcn_mfma_f32_16x16x32_bf16(af[m], bfv[n], acc[m][n], 0, 0, 0);
    __syncthreads();  // drains prefetch vmcnt + protects buffer reuse
  }

  // epilogue
#pragma unroll
  for (int n = 0; n < NR; n++) {
    const int col = col0 + wx * (BN / 2) + n * 16 + fr;
    const float bc = bias[(LAYER == 1 ? 0 : e * N) + col];
#pragma unroll
    for (int m = 0; m < 2; m++) {
      const int rloc = wy * 32 + m * 16 + kg * 4;
#pragma unroll
      for (int j = 0; j < 4; j++) {
        const float v = acc[m][n][j] + bc;
        if constexpr (LAYER == 1) {
          outb[(size_t)(rowbase + rloc + j) * N + col] = f2b(elu1(v));
        } else if constexpr (LAYER == 2) {
          const int slot = rowbase + rloc + j;
          if (slot < cnt) outb[(size_t)(start + slot) * N + col] = f2b(elu1(v));
        } else {
          const int slot = rowbase + rloc + j;
          if (slot < cnt) outf[(size_t)list[start + slot] * N + col] = v;
        }
      }
    }
  }
}

// ---------------- launch ----------------

extern "C" void kernel_launch(void* const* d_in, const int* in_sizes, int n_in,
                              void* d_out, int out_size, void* d_ws, size_t ws_size,
                              hipStream_t stream) {
  const float* x    = (const float*)d_in[0];
  const int*   cat  = (const int*)d_in[1];
  const float* W_in = (const float*)d_in[2];
  const float* b_in = (const float*)d_in[3];
  const float* W1   = (const float*)d_in[4];
  const float* b1   = (const float*)d_in[5];
  const float* W2   = (const float*)d_in[6];
  const float* b2   = (const float*)d_in[7];
  float* out = (float*)d_out;

  char* p = (char*)d_ws;
  u16* xb   = (u16*)p; p += (size_t)8192 * 512 * 2;    // 8 MB
  u16* midb = (u16*)p; p += (size_t)8192 * 1024 * 2;   // 16 MB
  u16* hb   = (u16*)p; p += (size_t)8192 * 512 * 2;    // 8 MB
  u16* wtin = (u16*)p; p += (size_t)1024 * 512 * 2;    // 1 MB
  u16* w1t  = (u16*)p; p += (size_t)8 * 512 * 1024 * 2;// 8 MB
  u16* w2t  = (u16*)p; p += (size_t)8 * 64 * 512 * 2;  // 0.5 MB
  int* list = (int*)p; p += (size_t)8192 * 4;          // 32 KB
  int* off  = (int*)p; p += 64;

  // converts
  cvt_f32_bf16_vec4<<<4096, 256, 0, stream>>>(x, xb);
  tcvt<<<dim3(32, 16, 1), dim3(32, 8), 0, stream>>>(W_in, wtin, 512, 1024);
  tcvt<<<dim3(16, 32, 8), dim3(32, 8), 0, stream>>>(W1, w1t, 1024, 512);
  tcvt<<<dim3(2, 16, 8), dim3(32, 8), 0, stream>>>(W2, w2t, 512, 64);

  // routing
  route_kernel<<<1, 1024, 0, stream>>>(cat, list, off);

  // layer 1: [8192,512] @ [512,1024] -> midb
  gemm_t<1, 128, 512, 1024><<<dim3(128, 8), 256, 0, stream>>>(
      xb, wtin, b_in, nullptr, nullptr, midb, nullptr);
  // layer 2 grouped: [cnt_e,1024] @ [1024,512] -> hb (compact)
  gemm_t<2, 128, 1024, 512><<<dim3(136, 4), 256, 0, stream>>>(
      midb, w1t, b1, list, off, hb, nullptr);
  // layer 3 grouped: [cnt_e,512] @ [512,64] -> out (scattered)
  gemm_t<3, 64, 512, 64><<<dim3(136, 1), 256, 0, stream>>>(
      hb, w2t, b2, list, off, nullptr, out);
}

// Round 3
// 76.285 us; speedup vs baseline: 1.7031x; 1.1114x over previous
//
#include <hip/hip_runtime.h>

typedef unsigned short u16;
typedef __bf16 bf16x8 __attribute__((ext_vector_type(8)));
typedef float f32x4 __attribute__((ext_vector_type(4)));

#define GLD_LDS(gptr, lptr) \
  __builtin_amdgcn_global_load_lds((const __attribute__((address_space(1))) void*)(gptr), \
                                   (__attribute__((address_space(3))) void*)(lptr), 16, 0, 0)

__device__ __forceinline__ u16 f2b(float f) {
  union { __bf16 h; u16 u; } v; v.h = (__bf16)f; return v.u;
}
__device__ __forceinline__ float elu1(float v) {
  return v > 0.f ? v : (__expf(v) - 1.f);
}

// ---------------- fused convert kernel ----------------
// blocks [0,128):    W_in [512][1024] f32 -> o0 [1024][512] bf16
// blocks [128,1152): W1 [8][1024][512]    -> o1 [8][512][1024]
// blocks [1152,1216):W2 [8][512][64]      -> o2 [8][64][512]
// blocks [1216,3264): x [8192*512] f32 -> bf16 straight copy
__global__ __launch_bounds__(256) void wcvt(const float* __restrict__ W_in,
                                            const float* __restrict__ W1,
                                            const float* __restrict__ W2,
                                            const float* __restrict__ x,
                                            u16* __restrict__ o0, u16* __restrict__ o1,
                                            u16* __restrict__ o2, u16* __restrict__ ox) {
  const int bid = blockIdx.x, tid = threadIdx.x;
  if (bid >= 1216) {
    const size_t base = (size_t)(bid - 1216) * 2048 + (size_t)tid * 8;
    float4 v0 = *reinterpret_cast<const float4*>(x + base);
    float4 v1 = *reinterpret_cast<const float4*>(x + base + 4);
    ushort4 a, b;
    a.x = f2b(v0.x); a.y = f2b(v0.y); a.z = f2b(v0.z); a.w = f2b(v0.w);
    b.x = f2b(v1.x); b.y = f2b(v1.y); b.z = f2b(v1.z); b.w = f2b(v1.w);
    *reinterpret_cast<ushort4*>(ox + base) = a;
    *reinterpret_cast<ushort4*>(ox + base + 4) = b;
    return;
  }
  const float* src; u16* dst; int R, C, tr, tc; size_t zoff;
  if (bid < 128) {
    src = W_in; dst = o0; R = 512; C = 1024; tr = bid >> 4; tc = bid & 15; zoff = 0;
  } else if (bid < 1152) {
    int t = bid - 128; int z = t >> 7, rem = t & 127;
    src = W1; dst = o1; R = 1024; C = 512; tr = rem >> 3; tc = rem & 7;
    zoff = (size_t)z * R * C;
  } else {
    int t = bid - 1152; int z = t >> 3;
    src = W2; dst = o2; R = 512; C = 64; tr = t & 7; tc = 0;
    zoff = (size_t)z * R * C;
  }
  __shared__ float tbuf[64][65];   // odd dword stride -> conflict-free column reads
  const float* sp = src + zoff + (size_t)(tr * 64) * C + tc * 64;
#pragma unroll
  for (int i = 0; i < 4; i++) {
    const int rr = (tid >> 4) + i * 16, f = tid & 15;
    float4 v = *reinterpret_cast<const float4*>(sp + (size_t)rr * C + f * 4);
    tbuf[rr][f * 4 + 0] = v.x; tbuf[rr][f * 4 + 1] = v.y;
    tbuf[rr][f * 4 + 2] = v.z; tbuf[rr][f * 4 + 3] = v.w;
  }
  __syncthreads();
  u16* dp = dst + zoff + (size_t)(tc * 64) * R + tr * 64;
#pragma unroll
  for (int i = 0; i < 4; i++) {
    const int u = tid + i * 256;
    const int c = u >> 4, rq = u & 15;
    ushort4 w;
    w.x = f2b(tbuf[rq * 4 + 0][c]); w.y = f2b(tbuf[rq * 4 + 1][c]);
    w.z = f2b(tbuf[rq * 4 + 2][c]); w.w = f2b(tbuf[rq * 4 + 3][c]);
    *reinterpret_cast<ushort4*>(dp + (size_t)c * R + rq * 4) = w;
  }
}

// ---------------- routing ----------------

__global__ void route_kernel(const int* __restrict__ cat, int* __restrict__ list,
                             int* __restrict__ off) {
  __shared__ int cnt[8];
  __shared__ int cur[8];
  __shared__ int offs[9];
  int t = threadIdx.x;
  if (t < 8) cnt[t] = 0;
  __syncthreads();
  for (int i = t; i < 8192; i += 1024) atomicAdd(&cnt[cat[i]], 1);
  __syncthreads();
  if (t == 0) {
    int s = 0;
    for (int e = 0; e < 8; e++) { offs[e] = s; s += cnt[e]; }
    offs[8] = s;
  }
  __syncthreads();
  if (t < 8) cur[t] = offs[t];
  if (t < 9) off[t] = offs[t];
  __syncthreads();
  for (int i = t; i < 8192; i += 1024) {
    int c = cat[i];
    int p = atomicAdd(&cur[c], 1);
    list[p] = i;
  }
}

// ---------------- unified pipelined GEMM (unchanged from round 2) ----------------

template<int LAYER, int BN, int K, int N>
__global__ __launch_bounds__(256, 4) void gemm_t(
    const u16* __restrict__ A, const u16* __restrict__ Bw,
    const float* __restrict__ bias,
    const int* __restrict__ list, const int* __restrict__ off,
    u16* __restrict__ outb, float* __restrict__ outf) {
  __shared__ alignas(16) u16 As[2][64 * 32];
  __shared__ alignas(16) u16 Bs[2][BN * 32];

  const int tid = threadIdx.x;
  const int wave = tid >> 6, lane = tid & 63;

  int e = 0, start = 0, cnt = 0, rowbase;
  if constexpr (LAYER == 1) {
    rowbase = blockIdx.x * 64;
  } else {
    int t = blockIdx.x;
    int found = -1;
    for (e = 0; e < 8; e++) {
      int tiles = (off[e + 1] - off[e] + 63) >> 6;
      if (t < tiles) { found = e; break; }
      t -= tiles;
    }
    if (found < 0) return;
    start = off[e];
    cnt = off[e + 1] - start;
    rowbase = t * 64;
  }
  const int col0 = blockIdx.y * BN;

  const int srow = tid >> 2, skc = tid & 3;
  const int kxs = (skc ^ (srow & 3)) * 8;

  const u16* a_src;
  if constexpr (LAYER == 1) {
    a_src = A + (size_t)(rowbase + srow) * K + kxs;
  } else if constexpr (LAYER == 2) {
    int slot = rowbase + srow;
    int gr = list[start + min(slot, cnt - 1)];
    a_src = A + (size_t)gr * K + kxs;
  } else {
    int slot = rowbase + srow;
    a_src = A + (size_t)(start + min(slot, cnt - 1)) * K + kxs;
  }
  const u16* Bbase = Bw + (LAYER == 1 ? (size_t)0 : (size_t)e * N * K);
  const u16* b_src0 = Bbase + (size_t)(col0 + srow) * K + kxs;
  const u16* b_src1 = Bbase + (size_t)(col0 + 64 + srow) * K + kxs;

  const int wbase = wave * 64 * 8;

  constexpr int NR = BN / 32;
  const int wy = wave & 1, wx = wave >> 1;
  const int fr = lane & 15, kg = lane >> 4;
  const int kx = (kg ^ (fr & 3)) * 8;
  const int ar0 = (wy * 32 + fr) * 32 + kx;
  const int br0 = (wx * (BN / 2) + fr) * 32 + kx;

  f32x4 acc[2][NR] = {};

  GLD_LDS(a_src, &As[0][wbase]);
  GLD_LDS(b_src0, &Bs[0][wbase]);
  if constexpr (BN == 128) GLD_LDS(b_src1, &Bs[0][2048 + wbase]);
  __syncthreads();

  constexpr int NK = K / 32;
  for (int t = 0; t < NK; ++t) {
    const int cur = t & 1;
    if (t + 1 < NK) {
      const int nxt = cur ^ 1;
      const int kt = (t + 1) * 32;
      GLD_LDS(a_src + kt, &As[nxt][wbase]);
      GLD_LDS(b_src0 + kt, &Bs[nxt][wbase]);
      if constexpr (BN == 128) GLD_LDS(b_src1 + kt, &Bs[nxt][2048 + wbase]);
    }
    bf16x8 af[2], bfv[NR];
#pragma unroll
    for (int m = 0; m < 2; m++) af[m] = *(const bf16x8*)&As[cur][ar0 + m * 16 * 32];
#pragma unroll
    for (int n = 0; n < NR; n++) bfv[n] = *(const bf16x8*)&Bs[cur][br0 + n * 16 * 32];
#pragma unroll
    for (int m = 0; m < 2; m++)
#pragma unroll
      for (int n = 0; n < NR; n++)
        acc[m][n] = __builtin_amdgcn_mfma_f32_16x16x32_bf16(af[m], bfv[n], acc[m][n], 0, 0, 0);
    __syncthreads();
  }

#pragma unroll
  for (int n = 0; n < NR; n++) {
    const int col = col0 + wx * (BN / 2) + n * 16 + fr;
    const float bc = bias[(LAYER == 1 ? 0 : e * N) + col];
#pragma unroll
    for (int m = 0; m < 2; m++) {
      const int rloc = wy * 32 + m * 16 + kg * 4;
#pragma unroll
      for (int j = 0; j < 4; j++) {
        const float v = acc[m][n][j] + bc;
        if constexpr (LAYER == 1) {
          outb[(size_t)(rowbase + rloc + j) * N + col] = f2b(elu1(v));
        } else if constexpr (LAYER == 2) {
          const int slot = rowbase + rloc + j;
          if (slot < cnt) outb[(size_t)(start + slot) * N + col] = f2b(elu1(v));
        } else {
          const int slot = rowbase + rloc + j;
          if (slot < cnt) outf[(size_t)list[start + slot] * N + col] = v;
        }
      }
    }
  }
}

// ---------------- launch ----------------

extern "C" void kernel_launch(void* const* d_in, const int* in_sizes, int n_in,
                              void* d_out, int out_size, void* d_ws, size_t ws_size,
                              hipStream_t stream) {
  const float* x    = (const float*)d_in[0];
  const int*   cat  = (const int*)d_in[1];
  const float* W_in = (const float*)d_in[2];
  const float* b_in = (const float*)d_in[3];
  const float* W1   = (const float*)d_in[4];
  const float* b1   = (const float*)d_in[5];
  const float* W2   = (const float*)d_in[6];
  const float* b2   = (const float*)d_in[7];
  float* out = (float*)d_out;

  char* p = (char*)d_ws;
  u16* xb   = (u16*)p; p += (size_t)8192 * 512 * 2;    // 8 MB
  u16* midb = (u16*)p; p += (size_t)8192 * 1024 * 2;   // 16 MB
  u16* hb   = (u16*)p; p += (size_t)8192 * 512 * 2;    // 8 MB
  u16* wtin = (u16*)p; p += (size_t)1024 * 512 * 2;    // 1 MB
  u16* w1t  = (u16*)p; p += (size_t)8 * 512 * 1024 * 2;// 8 MB
  u16* w2t  = (u16*)p; p += (size_t)8 * 64 * 512 * 2;  // 0.5 MB
  int* list = (int*)p; p += (size_t)8192 * 4;          // 32 KB
  int* off  = (int*)p; p += 64;

  // all conversions in one launch
  wcvt<<<3264, 256, 0, stream>>>(W_in, W1, W2, x, wtin, w1t, w2t, xb);

  // routing
  route_kernel<<<1, 1024, 0, stream>>>(cat, list, off);

  // layer 1: [8192,512] @ [512,1024] -> midb
  gemm_t<1, 128, 512, 1024><<<dim3(128, 8), 256, 0, stream>>>(
      xb, wtin, b_in, nullptr, nullptr, midb, nullptr);
  // layer 2 grouped: [cnt_e,1024] @ [1024,512] -> hb (compact)
  gemm_t<2, 128, 1024, 512><<<dim3(136, 4), 256, 0, stream>>>(
      midb, w1t, b1, list, off, hb, nullptr);
  // layer 3 grouped: [cnt_e,512] @ [512,64] -> out (scattered)
  gemm_t<3, 64, 512, 64><<<dim3(136, 1), 256, 0, stream>>>(
      hb, w2t, b2, list, off, nullptr, out);
}